// Round 6
// baseline (528.903 us; speedup 1.0000x reference)
//
#include <hip/hip_runtime.h>

#define N_NODES 50000
#define N_GRAPHS 512
#define N_EDGES 800000

typedef __attribute__((ext_vector_type(8))) short short8;
typedef __attribute__((ext_vector_type(8))) unsigned short ushort8;
typedef __attribute__((ext_vector_type(4))) float floatx4;

__device__ __forceinline__ float bf2f(unsigned short u) {
    union { unsigned int i; float f; } c;
    c.i = ((unsigned int)u) << 16;
    return c.f;
}
__device__ __forceinline__ unsigned short f2bf(float f) {
    union { float f; unsigned int i; } c;
    c.f = f;
    unsigned int u = c.i;
    return (unsigned short)((u + 0x7fffu + ((u >> 16) & 1u)) >> 16);
}

// ---------------- zero fill ----------------
__global__ void zero_kernel(int* __restrict__ p, int n) {
    int i = blockIdx.x * blockDim.x + threadIdx.x;
    if (i < n) p[i] = 0;
}

// ---------------- converts ----------------
__global__ void convert_x4(const float* __restrict__ in, unsigned short* __restrict__ out, int n4) {
    int i = blockIdx.x * blockDim.x + threadIdx.x;
    if (i >= n4) return;
    float4 v = ((const float4*)in)[i];
    ushort4 o;
    o.x = f2bf(v.x); o.y = f2bf(v.y); o.z = f2bf(v.z); o.w = f2bf(v.w);
    ((ushort4*)out)[i] = o;
}

__global__ void convert_w(const float* __restrict__ W1, const float* __restrict__ W2,
                          const float* __restrict__ W3, unsigned short* __restrict__ o1,
                          unsigned short* __restrict__ o2, unsigned short* __restrict__ o3) {
    int i = blockIdx.x * blockDim.x + threadIdx.x;  // 0..40959
    const float* src; unsigned short* dst; int base;
    if (i < 8192)        { src = W1; dst = o1; base = i; }
    else if (i < 24576)  { src = W2; dst = o2; base = i - 8192; }
    else if (i < 40960)  { src = W3; dst = o3; base = i - 24576; }
    else return;
    float4 v = ((const float4*)src)[base];
    ushort4 o;
    o.x = f2bf(v.x); o.y = f2bf(v.y); o.z = f2bf(v.z); o.w = f2bf(v.w);
    ((ushort4*)dst)[base] = o;
}

// ---------------- CSR build ----------------
__global__ void deg_hist(const int* __restrict__ dst, int* __restrict__ deg) {
    int e = blockIdx.x * blockDim.x + threadIdx.x;
    if (e < N_EDGES) atomicAdd(&deg[dst[e]], 1);
}

__global__ __launch_bounds__(1024) void scan1(const int* __restrict__ deg,
                                              int* __restrict__ rowptr,
                                              int* __restrict__ blocksum) {
    __shared__ int s[1024];
    int t = threadIdx.x;
    int i = blockIdx.x * 1024 + t;
    int v = (i < N_NODES) ? deg[i] : 0;
    s[t] = v;
    __syncthreads();
    for (int off = 1; off < 1024; off <<= 1) {
        int add = (t >= off) ? s[t - off] : 0;
        __syncthreads();
        s[t] += add;
        __syncthreads();
    }
    if (i < N_NODES) rowptr[i] = s[t] - v;  // exclusive
    if (t == 1023) blocksum[blockIdx.x] = s[t];
}

__global__ void scan2(int* __restrict__ blocksum, int nb) {
    if (threadIdx.x == 0 && blockIdx.x == 0) {
        int run = 0;
        for (int i = 0; i < nb; i++) { int v = blocksum[i]; blocksum[i] = run; run += v; }
    }
}

__global__ void scan3(int* __restrict__ rowptr, const int* __restrict__ blocksum,
                      int* __restrict__ cursor) {
    int i = blockIdx.x * blockDim.x + threadIdx.x;
    if (i < N_NODES) {
        int v = rowptr[i] + blocksum[i >> 10];
        rowptr[i] = v;
        cursor[i] = v;
    }
    if (i == 0) rowptr[N_NODES] = N_EDGES;
}

__global__ void scatter_csr(const int* __restrict__ src, const int* __restrict__ dst,
                            int* __restrict__ cursor, int* __restrict__ csr) {
    int e = blockIdx.x * blockDim.x + threadIdx.x;
    if (e < N_EDGES) {
        int pos = atomicAdd(&cursor[dst[e]], 1);
        csr[pos] = src[e];
    }
}

// ---- fused GIN layer: out = relu((h[n] + sum_{j in N(n)} h[j]) @ W^T + b) ----
// One block = 64 nodes x 256 out-cols. Gather aggregates directly into the
// LDS A-tile (MFMA fragment layout, xor-swizzled), then 4 waves run the MFMA
// loop (wave w owns cols w*64..w*64+63), W fragments read from global (L2-hot).
template <int K>
__global__ __launch_bounds__(256) void gin_fused(
    const unsigned short* __restrict__ h, const int* __restrict__ rowptr,
    const int* __restrict__ csr, const unsigned short* __restrict__ W,
    const float* __restrict__ bias, unsigned short* __restrict__ out) {
    const int KC = K / 32;   // k-chunks of 32
    __shared__ short8 As[K * 8];  // 64 rows x K cols bf16, fragment order

    int t = threadIdx.x;
    int rowbase = blockIdx.x * 64;

    // ---- gather phase: fill As with agg rows ----
    const int TPN = K / 8;       // lanes per row (ushort8 = 16B each)
    const int NPB = 256 / TPN;   // rows per pass
#pragma unroll
    for (int pass = 0; pass < 64 / NPB; ++pass) {
        int r = pass * NPB + t / TPN;
        int c8 = t % TPN;
        int n = rowbase + r;
        if (n >= N_NODES) n = N_NODES - 1;
        const ushort8* hp = (const ushort8*)h + c8;
        ushort8 s = hp[(size_t)n * TPN];
        float acc[8];
#pragma unroll
        for (int j = 0; j < 8; j++) acc[j] = bf2f(s[j]);
        int p = rowptr[n], end = rowptr[n + 1];
        for (; p + 4 <= end; p += 4) {
            int j0 = csr[p], j1 = csr[p + 1], j2 = csr[p + 2], j3 = csr[p + 3];
            ushort8 v0 = hp[(size_t)j0 * TPN];
            ushort8 v1 = hp[(size_t)j1 * TPN];
            ushort8 v2 = hp[(size_t)j2 * TPN];
            ushort8 v3 = hp[(size_t)j3 * TPN];
#pragma unroll
            for (int j = 0; j < 8; j++)
                acc[j] += (bf2f(v0[j]) + bf2f(v1[j])) + (bf2f(v2[j]) + bf2f(v3[j]));
        }
        for (; p < end; ++p) {
            int jj = csr[p];
            ushort8 v = hp[(size_t)jj * TPN];
#pragma unroll
            for (int j = 0; j < 8; j++) acc[j] += bf2f(v[j]);
        }
        short8 o;
#pragma unroll
        for (int j = 0; j < 8; j++) o[j] = (short)f2bf(acc[j]);
        int c = c8 >> 2, kc = c8 & 3;
        int slot = ((r >> 4) * KC + c) * 64 + kc * 16 + ((r & 15) ^ (kc << 2));
        As[slot] = o;
    }
    __syncthreads();

    // ---- MFMA phase ----
    int wave = t >> 6, lane = t & 63;
    int lkc = lane >> 4, lr = lane & 15;
    int rslot = lkc * 16 + (lr ^ (lkc << 2));
    const int wcol = wave * 64;

    floatx4 acc4[4][4];
#pragma unroll
    for (int i = 0; i < 4; i++)
#pragma unroll
        for (int j = 0; j < 4; j++) acc4[i][j] = (floatx4)(0.f);

#pragma unroll
    for (int c = 0; c < KC; c++) {
        short8 af[4], wf[4];
#pragma unroll
        for (int mt = 0; mt < 4; mt++) af[mt] = As[(mt * KC + c) * 64 + rslot];
#pragma unroll
        for (int nt = 0; nt < 4; nt++) {
            int col = wcol + nt * 16 + lr;
            wf[nt] = *(const short8*)(W + (size_t)col * K + c * 32 + lkc * 8);
        }
#pragma unroll
        for (int mt = 0; mt < 4; mt++)
#pragma unroll
            for (int nt = 0; nt < 4; nt++)
                acc4[mt][nt] = __builtin_amdgcn_mfma_f32_16x16x32_bf16(
                    af[mt], wf[nt], acc4[mt][nt], 0, 0, 0);
    }

    // epilogue: C/D layout col=lane&15, row=(lane>>4)*4+reg
    int r0 = lkc * 4;
#pragma unroll
    for (int mt = 0; mt < 4; mt++) {
#pragma unroll
        for (int reg = 0; reg < 4; reg++) {
            int row = rowbase + mt * 16 + r0 + reg;
            if (row >= N_NODES) continue;
#pragma unroll
            for (int nt = 0; nt < 4; nt++) {
                int col = wcol + nt * 16 + lr;
                float v = acc4[mt][nt][reg] + bias[col];
                out[(size_t)row * 256 + col] = f2bf(fmaxf(v, 0.f));
            }
        }
    }
}

// ---------------- mean pool (bf16 in, fp32 out), batch sorted --------------
__global__ __launch_bounds__(256) void pool_mean(const unsigned short* __restrict__ h,
                                                 const int* __restrict__ batch,
                                                 float* __restrict__ hg) {
    int g = blockIdx.x;
    int t = threadIdx.x;
    int lo = 0, hi = N_NODES;
    while (lo < hi) { int m = (lo + hi) >> 1; if (batch[m] < g) lo = m + 1; else hi = m; }
    int start = lo;
    lo = 0; hi = N_NODES;
    while (lo < hi) { int m = (lo + hi) >> 1; if (batch[m] < g + 1) lo = m + 1; else hi = m; }
    int end = lo;
    float acc = 0.f;
    for (int r = start; r < end; ++r) acc += bf2f(h[(size_t)r * 256 + t]);
    float inv = 1.0f / fmaxf((float)(end - start), 1.0f);
    hg[g * 256 + t] = acc * inv;
}

// ---------------- MLP head ----------------
__global__ __launch_bounds__(128) void head_kernel(
    const float* __restrict__ hg_in,
    const float* __restrict__ Wf1, const float* __restrict__ bf1,
    const float* __restrict__ Wf2, const float* __restrict__ bf2,
    float* __restrict__ out) {
    __shared__ float hg[256];
    __shared__ float hid[128];
    int g = blockIdx.x;
    int t = threadIdx.x;
    hg[t] = hg_in[g * 256 + t];
    hg[t + 128] = hg_in[g * 256 + t + 128];
    __syncthreads();
    float acc = bf1[t];
    for (int c = 0; c < 256; c++) acc += hg[c] * Wf1[t * 256 + c];
    hid[t] = fmaxf(acc, 0.f);
    __syncthreads();
    if (t < 10) {
        float a = bf2[t];
        for (int j = 0; j < 128; j++) a += hid[j] * Wf2[t * 128 + j];
        out[g * 10 + t] = a;
    }
}

extern "C" void kernel_launch(void* const* d_in, const int* in_sizes, int n_in,
                              void* d_out, int out_size, void* d_ws, size_t ws_size,
                              hipStream_t stream) {
    const float* x   = (const float*)d_in[0];
    const int*  edge = (const int*)d_in[1];
    const int*  batch= (const int*)d_in[2];
    const float* W1  = (const float*)d_in[3];
    const float* b1  = (const float*)d_in[4];
    const float* W2  = (const float*)d_in[5];
    const float* b2  = (const float*)d_in[6];
    const float* W3  = (const float*)d_in[7];
    const float* b3  = (const float*)d_in[8];
    const float* Wf1 = (const float*)d_in[9];
    const float* bf1 = (const float*)d_in[10];
    const float* Wf2 = (const float*)d_in[11];
    const float* bf2 = (const float*)d_in[12];
    const int* src = edge;
    const int* dst = edge + N_EDGES;

    char* wsb = (char*)d_ws;
    size_t off = 0;
    auto alloc = [&](size_t bytes) { void* p = wsb + off; off += (bytes + 255) & ~(size_t)255; return p; };
    unsigned short* x_bf  = (unsigned short*)alloc((size_t)N_NODES * 128 * 2);
    unsigned short* hA_bf = (unsigned short*)alloc((size_t)N_NODES * 256 * 2);
    unsigned short* hB_bf = (unsigned short*)alloc((size_t)N_NODES * 256 * 2);
    unsigned short* W1bf  = (unsigned short*)alloc(256 * 128 * 2);
    unsigned short* W2bf  = (unsigned short*)alloc(256 * 256 * 2);
    unsigned short* W3bf  = (unsigned short*)alloc(256 * 256 * 2);
    float*          hg    = (float*)alloc(N_GRAPHS * 256 * 4);
    int* rowptr   = (int*)alloc((N_NODES + 4) * 4);
    int* cursor   = (int*)alloc(N_NODES * 4);
    int* deg      = (int*)alloc(N_NODES * 4);
    int* csr      = (int*)alloc(N_EDGES * 4);
    int* blocksum = (int*)alloc(64 * 4);

    const int NB_SCAN = (N_NODES + 1023) / 1024;  // 49

    // ---- CSR build (by dst) ----
    zero_kernel<<<(N_NODES + 255) / 256, 256, 0, stream>>>(deg, N_NODES);
    deg_hist<<<(N_EDGES + 255) / 256, 256, 0, stream>>>(dst, deg);
    scan1<<<NB_SCAN, 1024, 0, stream>>>(deg, rowptr, blocksum);
    scan2<<<1, 64, 0, stream>>>(blocksum, NB_SCAN);
    scan3<<<NB_SCAN, 1024, 0, stream>>>(rowptr, blocksum, cursor);
    scatter_csr<<<(N_EDGES + 255) / 256, 256, 0, stream>>>(src, dst, cursor, csr);

    // ---- converts ----
    convert_x4<<<(N_NODES * 128 / 4 + 255) / 256, 256, 0, stream>>>(x, x_bf, N_NODES * 128 / 4);
    convert_w<<<(40960 + 255) / 256, 256, 0, stream>>>(W1, W2, W3, W1bf, W2bf, W3bf);

    const int NBLK = (N_NODES + 63) / 64;  // 782

    // ---- fused layers ----
    gin_fused<128><<<NBLK, 256, 0, stream>>>(x_bf, rowptr, csr, W1bf, b1, hA_bf);
    gin_fused<256><<<NBLK, 256, 0, stream>>>(hA_bf, rowptr, csr, W2bf, b2, hB_bf);
    gin_fused<256><<<NBLK, 256, 0, stream>>>(hB_bf, rowptr, csr, W3bf, b3, hA_bf);

    // ---- mean pool + head ----
    pool_mean<<<N_GRAPHS, 256, 0, stream>>>(hA_bf, batch, hg);
    head_kernel<<<N_GRAPHS, 128, 0, stream>>>(hg, Wf1, bf1, Wf2, bf2, (float*)d_out);
}

// Round 7
// 456.946 us; speedup vs baseline: 1.1575x; 1.1575x over previous
//
#include <hip/hip_runtime.h>

#define N_NODES 50000
#define N_GRAPHS 512
#define N_EDGES 800000

typedef __attribute__((ext_vector_type(8))) short short8;
typedef __attribute__((ext_vector_type(8))) unsigned short ushort8;
typedef __attribute__((ext_vector_type(4))) float floatx4;

__device__ __forceinline__ float bf2f(unsigned short u) {
    union { unsigned int i; float f; } c;
    c.i = ((unsigned int)u) << 16;
    return c.f;
}
__device__ __forceinline__ unsigned short f2bf(float f) {
    union { float f; unsigned int i; } c;
    c.f = f;
    unsigned int u = c.i;
    return (unsigned short)((u + 0x7fffu + ((u >> 16) & 1u)) >> 16);
}

// ---------------- fused converts: x (1.6M float4) + W1/W2/W3 (40960) -------
__global__ void convert_all(const float* __restrict__ x, const float* __restrict__ W1,
                            const float* __restrict__ W2, const float* __restrict__ W3,
                            unsigned short* __restrict__ xo, unsigned short* __restrict__ o1,
                            unsigned short* __restrict__ o2, unsigned short* __restrict__ o3) {
    int i = blockIdx.x * blockDim.x + threadIdx.x;  // 0..1640959
    const float* src; unsigned short* dst; int base;
    if (i < 1600000)      { src = x;  dst = xo; base = i; }
    else {
        int j = i - 1600000;
        if (j < 8192)       { src = W1; dst = o1; base = j; }
        else if (j < 24576) { src = W2; dst = o2; base = j - 8192; }
        else if (j < 40960) { src = W3; dst = o3; base = j - 24576; }
        else return;
    }
    float4 v = ((const float4*)src)[base];
    ushort4 o;
    o.x = f2bf(v.x); o.y = f2bf(v.y); o.z = f2bf(v.z); o.w = f2bf(v.w);
    ((ushort4*)dst)[base] = o;
}

// ---------------- CSR build ----------------
__global__ void deg_hist(const int* __restrict__ dst, int* __restrict__ deg) {
    int e = blockIdx.x * blockDim.x + threadIdx.x;
    if (e < N_EDGES) atomicAdd(&deg[dst[e]], 1);
}

__global__ __launch_bounds__(1024) void scan1(const int* __restrict__ deg,
                                              int* __restrict__ rowptr,
                                              int* __restrict__ blocksum) {
    __shared__ int s[1024];
    int t = threadIdx.x;
    int i = blockIdx.x * 1024 + t;
    int v = (i < N_NODES) ? deg[i] : 0;
    s[t] = v;
    __syncthreads();
    for (int off = 1; off < 1024; off <<= 1) {
        int add = (t >= off) ? s[t - off] : 0;
        __syncthreads();
        s[t] += add;
        __syncthreads();
    }
    if (i < N_NODES) rowptr[i] = s[t] - v;  // exclusive
    if (t == 1023) blocksum[blockIdx.x] = s[t];
}

__global__ void scan2(int* __restrict__ blocksum, int nb) {
    if (threadIdx.x == 0 && blockIdx.x == 0) {
        int run = 0;
        for (int i = 0; i < nb; i++) { int v = blocksum[i]; blocksum[i] = run; run += v; }
    }
}

__global__ void scan3(int* __restrict__ rowptr, const int* __restrict__ blocksum,
                      int* __restrict__ cursor) {
    int i = blockIdx.x * blockDim.x + threadIdx.x;
    if (i < N_NODES) {
        int v = rowptr[i] + blocksum[i >> 10];
        rowptr[i] = v;
        cursor[i] = v;
    }
    if (i == 0) rowptr[N_NODES] = N_EDGES;
}

__global__ void scatter_csr(const int* __restrict__ src, const int* __restrict__ dst,
                            int* __restrict__ cursor, int* __restrict__ csr) {
    int e = blockIdx.x * blockDim.x + threadIdx.x;
    if (e < N_EDGES) {
        int pos = atomicAdd(&cursor[dst[e]], 1);
        csr[pos] = src[e];
    }
}

// ---- bf16 gather: 16 lanes/row (32B per lane via 2 loads), unroll-4 -------
// 16 concurrent row-streams per wave; agg[n] = h[n] + sum_{j in N(n)} h[j]
template <int C>
__global__ __launch_bounds__(256) void gather_bf(const unsigned short* __restrict__ h,
                                                 const int* __restrict__ rowptr,
                                                 const int* __restrict__ csr,
                                                 unsigned short* __restrict__ agg) {
    const int LPR = C / 16;      // lanes per row
    const int RPB = 256 / LPR;   // rows per block
    const int ST = C / 8;        // row stride in ushort8
    int t = threadIdx.x;
    int n = blockIdx.x * RPB + t / LPR;
    if (n >= N_NODES) return;
    int cl = t % LPR;
    const ushort8* hp = (const ushort8*)h + cl * 2;
    ushort8 s0 = hp[(size_t)n * ST], s1 = hp[(size_t)n * ST + 1];
    float acc[16];
#pragma unroll
    for (int j = 0; j < 8; j++) { acc[j] = bf2f(s0[j]); acc[8 + j] = bf2f(s1[j]); }
    int p = rowptr[n], end = rowptr[n + 1];
    for (; p + 4 <= end; p += 4) {
        int j0 = csr[p], j1 = csr[p + 1], j2 = csr[p + 2], j3 = csr[p + 3];
        ushort8 a0 = hp[(size_t)j0 * ST], b0 = hp[(size_t)j0 * ST + 1];
        ushort8 a1 = hp[(size_t)j1 * ST], b1 = hp[(size_t)j1 * ST + 1];
        ushort8 a2 = hp[(size_t)j2 * ST], b2 = hp[(size_t)j2 * ST + 1];
        ushort8 a3 = hp[(size_t)j3 * ST], b3 = hp[(size_t)j3 * ST + 1];
#pragma unroll
        for (int j = 0; j < 8; j++) {
            acc[j]     += (bf2f(a0[j]) + bf2f(a1[j])) + (bf2f(a2[j]) + bf2f(a3[j]));
            acc[8 + j] += (bf2f(b0[j]) + bf2f(b1[j])) + (bf2f(b2[j]) + bf2f(b3[j]));
        }
    }
    for (; p < end; ++p) {
        int jj = csr[p];
        ushort8 a = hp[(size_t)jj * ST], b = hp[(size_t)jj * ST + 1];
#pragma unroll
        for (int j = 0; j < 8; j++) { acc[j] += bf2f(a[j]); acc[8 + j] += bf2f(b[j]); }
    }
    ushort8 o0, o1;
#pragma unroll
    for (int j = 0; j < 8; j++) { o0[j] = f2bf(acc[j]); o1[j] = f2bf(acc[8 + j]); }
    ushort8* op = (ushort8*)agg + cl * 2;
    op[(size_t)n * ST] = o0;
    op[(size_t)n * ST + 1] = o1;
}

// ---- MFMA GEMM: out = relu(A[M,K]bf16 @ W[256,K]bf16^T + b) -> bf16 -------
__global__ __launch_bounds__(256) void gemm_mfma(
    const unsigned short* __restrict__ A, const unsigned short* __restrict__ W,
    const float* __restrict__ bias, unsigned short* __restrict__ Cbf, int M, int K) {
    const int BM = 128, BK = 32;
    __shared__ short8 As[8 * 64];
    __shared__ short8 Ws[8 * 64];

    int tid = threadIdx.x;
    int wave = tid >> 6, lane = tid & 63;
    int wm = wave & 1, wn = wave >> 1;
    int rowbase = blockIdx.x * BM;
    int colbase = blockIdx.y * 128;
    int lkc = lane >> 4, lr = lane & 15;
    int rslot = lkc * 16 + (lr ^ (lkc << 2));

    floatx4 acc[4][4];
#pragma unroll
    for (int i = 0; i < 4; i++)
#pragma unroll
        for (int j = 0; j < 4; j++) acc[i][j] = (floatx4)(0.f);

    for (int k0 = 0; k0 < K; k0 += BK) {
#pragma unroll
        for (int i = 0; i < 2; i++) {
            int idx = i * 256 + tid;
            int row = idx >> 2, kc = idx & 3;
            int slot = (row >> 4) * 64 + kc * 16 + ((row & 15) ^ (kc << 2));
            int ar = rowbase + row;
            if (ar >= M) ar = M - 1;
            As[slot] = *(const short8*)(A + (size_t)ar * K + k0 + kc * 8);
            Ws[slot] = *(const short8*)(W + (size_t)(colbase + row) * K + k0 + kc * 8);
        }
        __syncthreads();

        short8 af[4], wf[4];
#pragma unroll
        for (int mt = 0; mt < 4; mt++) af[mt] = As[(wm * 4 + mt) * 64 + rslot];
#pragma unroll
        for (int nt = 0; nt < 4; nt++) wf[nt] = Ws[(wn * 4 + nt) * 64 + rslot];
#pragma unroll
        for (int mt = 0; mt < 4; mt++)
#pragma unroll
            for (int nt = 0; nt < 4; nt++)
                acc[mt][nt] = __builtin_amdgcn_mfma_f32_16x16x32_bf16(
                    af[mt], wf[nt], acc[mt][nt], 0, 0, 0);
        __syncthreads();
    }

    int ccol = lane & 15;
    int r0 = (lane >> 4) * 4;
#pragma unroll
    for (int mt = 0; mt < 4; mt++) {
#pragma unroll
        for (int reg = 0; reg < 4; reg++) {
            int row = rowbase + (wm * 4 + mt) * 16 + r0 + reg;
            if (row >= M) continue;
#pragma unroll
            for (int nt = 0; nt < 4; nt++) {
                int col = colbase + (wn * 4 + nt) * 16 + ccol;
                float v = acc[mt][nt][reg] + bias[col];
                Cbf[(size_t)row * 256 + col] = f2bf(fmaxf(v, 0.f));
            }
        }
    }
}

// ------- fused mean-pool + MLP head: one block (256 thr) per graph ---------
__global__ __launch_bounds__(256) void pool_head(
    const unsigned short* __restrict__ h, const int* __restrict__ batch,
    const float* __restrict__ Wf1, const float* __restrict__ bf1,
    const float* __restrict__ Wf2, const float* __restrict__ bf2,
    float* __restrict__ out) {
    __shared__ float hg[256];
    __shared__ float hid[128];
    int g = blockIdx.x;
    int t = threadIdx.x;
    int lo = 0, hi = N_NODES;
    while (lo < hi) { int m = (lo + hi) >> 1; if (batch[m] < g) lo = m + 1; else hi = m; }
    int start = lo;
    lo = 0; hi = N_NODES;
    while (lo < hi) { int m = (lo + hi) >> 1; if (batch[m] < g + 1) lo = m + 1; else hi = m; }
    int end = lo;
    float acc = 0.f;
    for (int r = start; r < end; ++r) acc += bf2f(h[(size_t)r * 256 + t]);
    hg[t] = acc / fmaxf((float)(end - start), 1.0f);
    __syncthreads();
    float a1 = 0.f;
    if (t < 128) {
        a1 = bf1[t];
        for (int c = 0; c < 256; c++) a1 += hg[c] * Wf1[t * 256 + c];
        hid[t] = fmaxf(a1, 0.f);
    }
    __syncthreads();
    if (t < 10) {
        float a = bf2[t];
        for (int j = 0; j < 128; j++) a += hid[j] * Wf2[t * 128 + j];
        out[g * 10 + t] = a;
    }
}

extern "C" void kernel_launch(void* const* d_in, const int* in_sizes, int n_in,
                              void* d_out, int out_size, void* d_ws, size_t ws_size,
                              hipStream_t stream) {
    const float* x   = (const float*)d_in[0];
    const int*  edge = (const int*)d_in[1];
    const int*  batch= (const int*)d_in[2];
    const float* W1  = (const float*)d_in[3];
    const float* b1  = (const float*)d_in[4];
    const float* W2  = (const float*)d_in[5];
    const float* b2  = (const float*)d_in[6];
    const float* W3  = (const float*)d_in[7];
    const float* b3  = (const float*)d_in[8];
    const float* Wf1 = (const float*)d_in[9];
    const float* bf1 = (const float*)d_in[10];
    const float* Wf2 = (const float*)d_in[11];
    const float* bf2 = (const float*)d_in[12];
    const int* src = edge;
    const int* dst = edge + N_EDGES;

    char* wsb = (char*)d_ws;
    size_t off = 0;
    auto alloc = [&](size_t bytes) { void* p = wsb + off; off += (bytes + 255) & ~(size_t)255; return p; };
    unsigned short* x_bf  = (unsigned short*)alloc((size_t)N_NODES * 128 * 2);
    unsigned short* agg_bf= (unsigned short*)alloc((size_t)N_NODES * 256 * 2);
    unsigned short* hA_bf = (unsigned short*)alloc((size_t)N_NODES * 256 * 2);
    unsigned short* hB_bf = (unsigned short*)alloc((size_t)N_NODES * 256 * 2);
    unsigned short* W1bf  = (unsigned short*)alloc(256 * 128 * 2);
    unsigned short* W2bf  = (unsigned short*)alloc(256 * 256 * 2);
    unsigned short* W3bf  = (unsigned short*)alloc(256 * 256 * 2);
    int* rowptr   = (int*)alloc((N_NODES + 4) * 4);
    int* cursor   = (int*)alloc(N_NODES * 4);
    int* deg      = (int*)alloc(N_NODES * 4);
    int* csr      = (int*)alloc(N_EDGES * 4);
    int* blocksum = (int*)alloc(64 * 4);

    const int NB_SCAN = (N_NODES + 1023) / 1024;  // 49

    // ---- CSR build (by dst) ----
    hipMemsetAsync(deg, 0, N_NODES * sizeof(int), stream);
    deg_hist<<<(N_EDGES + 255) / 256, 256, 0, stream>>>(dst, deg);
    scan1<<<NB_SCAN, 1024, 0, stream>>>(deg, rowptr, blocksum);
    scan2<<<1, 64, 0, stream>>>(blocksum, NB_SCAN);
    scan3<<<NB_SCAN, 1024, 0, stream>>>(rowptr, blocksum, cursor);
    scatter_csr<<<(N_EDGES + 255) / 256, 256, 0, stream>>>(src, dst, cursor, csr);

    // ---- converts (x + all weights, one launch) ----
    convert_all<<<(1640960 + 255) / 256, 256, 0, stream>>>(x, W1, W2, W3, x_bf, W1bf, W2bf, W3bf);

    dim3 ggrid((N_NODES + 127) / 128, 2);  // 391 x 2

    // ---- layer 1 (K=128): 32 rows/block ----
    gather_bf<128><<<(N_NODES + 31) / 32, 256, 0, stream>>>(x_bf, rowptr, csr, agg_bf);
    gemm_mfma<<<ggrid, 256, 0, stream>>>(agg_bf, W1bf, b1, hA_bf, N_NODES, 128);

    // ---- layer 2 (K=256): 16 rows/block ----
    gather_bf<256><<<(N_NODES + 15) / 16, 256, 0, stream>>>(hA_bf, rowptr, csr, agg_bf);
    gemm_mfma<<<ggrid, 256, 0, stream>>>(agg_bf, W2bf, b2, hB_bf, N_NODES, 256);

    // ---- layer 3 (K=256) ----
    gather_bf<256><<<(N_NODES + 15) / 16, 256, 0, stream>>>(hB_bf, rowptr, csr, agg_bf);
    gemm_mfma<<<ggrid, 256, 0, stream>>>(agg_bf, W3bf, b3, hA_bf, N_NODES, 256);

    // ---- fused mean pool + head ----
    pool_head<<<N_GRAPHS, 256, 0, stream>>>(hA_bf, batch, Wf1, bf1, Wf2, bf2, (float*)d_out);
}

// Round 8
// 454.431 us; speedup vs baseline: 1.1639x; 1.0055x over previous
//
#include <hip/hip_runtime.h>

#define N_NODES 50000
#define N_GRAPHS 512
#define N_EDGES 800000

typedef __attribute__((ext_vector_type(8))) short short8;
typedef __attribute__((ext_vector_type(8))) unsigned short ushort8;
typedef __attribute__((ext_vector_type(4))) float floatx4;

__device__ __forceinline__ float bf2f(unsigned short u) {
    union { unsigned int i; float f; } c;
    c.i = ((unsigned int)u) << 16;
    return c.f;
}
__device__ __forceinline__ unsigned short f2bf(float f) {
    union { float f; unsigned int i; } c;
    c.f = f;
    unsigned int u = c.i;
    return (unsigned short)((u + 0x7fffu + ((u >> 16) & 1u)) >> 16);
}

// async 16B global -> LDS (lane-ordered destination: ldsbase + lane*16)
__device__ __forceinline__ void g2lds16(const unsigned short* g, void* lds) {
    __builtin_amdgcn_global_load_lds(
        (const __attribute__((address_space(1))) void*)g,
        (__attribute__((address_space(3))) void*)lds, 16, 0, 0);
}

// ---------------- fused converts: x (1.6M float4) + W1/W2/W3 (40960) -------
__global__ void convert_all(const float* __restrict__ x, const float* __restrict__ W1,
                            const float* __restrict__ W2, const float* __restrict__ W3,
                            unsigned short* __restrict__ xo, unsigned short* __restrict__ o1,
                            unsigned short* __restrict__ o2, unsigned short* __restrict__ o3) {
    int i = blockIdx.x * blockDim.x + threadIdx.x;  // 0..1640959
    const float* src; unsigned short* dst; int base;
    if (i < 1600000)      { src = x;  dst = xo; base = i; }
    else {
        int j = i - 1600000;
        if (j < 8192)       { src = W1; dst = o1; base = j; }
        else if (j < 24576) { src = W2; dst = o2; base = j - 8192; }
        else if (j < 40960) { src = W3; dst = o3; base = j - 24576; }
        else return;
    }
    float4 v = ((const float4*)src)[base];
    ushort4 o;
    o.x = f2bf(v.x); o.y = f2bf(v.y); o.z = f2bf(v.z); o.w = f2bf(v.w);
    ((ushort4*)dst)[base] = o;
}

// ---------------- CSR build ----------------
__global__ void deg_hist(const int* __restrict__ dst, int* __restrict__ deg) {
    int e = blockIdx.x * blockDim.x + threadIdx.x;
    if (e < N_EDGES) atomicAdd(&deg[dst[e]], 1);
}

__global__ __launch_bounds__(1024) void scan1(const int* __restrict__ deg,
                                              int* __restrict__ rowptr,
                                              int* __restrict__ blocksum) {
    __shared__ int s[1024];
    int t = threadIdx.x;
    int i = blockIdx.x * 1024 + t;
    int v = (i < N_NODES) ? deg[i] : 0;
    s[t] = v;
    __syncthreads();
    for (int off = 1; off < 1024; off <<= 1) {
        int add = (t >= off) ? s[t - off] : 0;
        __syncthreads();
        s[t] += add;
        __syncthreads();
    }
    if (i < N_NODES) rowptr[i] = s[t] - v;  // exclusive
    if (t == 1023) blocksum[blockIdx.x] = s[t];
}

__global__ void scan2(int* __restrict__ blocksum, int nb) {
    if (threadIdx.x == 0 && blockIdx.x == 0) {
        int run = 0;
        for (int i = 0; i < nb; i++) { int v = blocksum[i]; blocksum[i] = run; run += v; }
    }
}

__global__ void scan3(int* __restrict__ rowptr, const int* __restrict__ blocksum,
                      int* __restrict__ cursor) {
    int i = blockIdx.x * blockDim.x + threadIdx.x;
    if (i < N_NODES) {
        int v = rowptr[i] + blocksum[i >> 10];
        rowptr[i] = v;
        cursor[i] = v;
    }
    if (i == 0) rowptr[N_NODES] = N_EDGES;
}

__global__ void scatter_csr(const int* __restrict__ src, const int* __restrict__ dst,
                            int* __restrict__ cursor, int* __restrict__ csr) {
    int e = blockIdx.x * blockDim.x + threadIdx.x;
    if (e < N_EDGES) {
        int pos = atomicAdd(&cursor[dst[e]], 1);
        csr[pos] = src[e];
    }
}

// ---- bf16 gather (R5 proven config): 16B/lane, unroll-4 -------------------
template <int C>
__global__ __launch_bounds__(256) void gather_bf(const unsigned short* __restrict__ h,
                                                 const int* __restrict__ rowptr,
                                                 const int* __restrict__ csr,
                                                 unsigned short* __restrict__ agg) {
    const int TPN = C / 8;       // lanes per node (ushort8 = 16B each)
    const int NPB = 256 / TPN;
    int t = threadIdx.x;
    int n = blockIdx.x * NPB + t / TPN;
    if (n >= N_NODES) return;
    int c8 = t % TPN;
    const ushort8* hp = (const ushort8*)h + c8;
    ushort8 s = hp[(size_t)n * TPN];
    float acc[8];
#pragma unroll
    for (int j = 0; j < 8; j++) acc[j] = bf2f(s[j]);
    int p = rowptr[n], end = rowptr[n + 1];
    for (; p + 4 <= end; p += 4) {
        int j0 = csr[p], j1 = csr[p + 1], j2 = csr[p + 2], j3 = csr[p + 3];
        ushort8 v0 = hp[(size_t)j0 * TPN];
        ushort8 v1 = hp[(size_t)j1 * TPN];
        ushort8 v2 = hp[(size_t)j2 * TPN];
        ushort8 v3 = hp[(size_t)j3 * TPN];
#pragma unroll
        for (int j = 0; j < 8; j++)
            acc[j] += (bf2f(v0[j]) + bf2f(v1[j])) + (bf2f(v2[j]) + bf2f(v3[j]));
    }
    for (; p < end; ++p) {
        int jj = csr[p];
        ushort8 v = hp[(size_t)jj * TPN];
#pragma unroll
        for (int j = 0; j < 8; j++) acc[j] += bf2f(v[j]);
    }
    ushort8 o;
#pragma unroll
    for (int j = 0; j < 8; j++) o[j] = f2bf(acc[j]);
    ((ushort8*)agg)[(size_t)n * TPN + c8] = o;
}

// ---- MFMA GEMM with global_load_lds staging -------------------------------
// out = relu(A[M,K]bf16 @ W[256,K]bf16^T + b) -> bf16. BM=128, BN=128
// (blockIdx.y in {0,1}), BK=32, 256 threads = 4 waves (2x2).
// LDS slot s (16B units): mtile=s>>6, kc=(s>>4)&3, rx=s&15 holds
// A[rowbase + mtile*16 + (rx^(kc<<2))][k0 + kc*8 ..+8]. Hardware writes
// call i, thread tid -> slot i*256+tid, so each lane fetches the global
// address belonging at its slot (source-side swizzle).
template <int K>
__global__ __launch_bounds__(256) void gemm_mfma(
    const unsigned short* __restrict__ A, const unsigned short* __restrict__ W,
    const float* __restrict__ bias, unsigned short* __restrict__ Cbf, int M) {
    __shared__ short8 As[512];  // 8 KB
    __shared__ short8 Ws[512];  // 8 KB

    int tid = threadIdx.x;
    int wave = tid >> 6, lane = tid & 63;
    int wm = wave & 1, wn = wave >> 1;
    int rowbase = blockIdx.x * 128;
    int colbase = blockIdx.y * 128;
    int lkc = lane >> 4, lr = lane & 15;
    int rslot = lkc * 16 + (lr ^ (lkc << 2));

    // per-lane source row offsets for the two staging calls (i=0,1)
    int rsw = lr ^ (lkc << 2);
    int row0 = (0 * 4 + wave) * 16 + rsw;   // mtile = i*4 + wave
    int row1 = (1 * 4 + wave) * 16 + rsw;
    int ar0 = rowbase + row0; if (ar0 >= M) ar0 = M - 1;
    int ar1 = rowbase + row1; if (ar1 >= M) ar1 = M - 1;
    int wr0 = colbase + row0;
    int wr1 = colbase + row1;
    // wave-uniform LDS bases (16B units): i*256 + wave*64
    char* asb0 = (char*)As + (size_t)(0 * 256 + wave * 64) * 16;
    char* asb1 = (char*)As + (size_t)(1 * 256 + wave * 64) * 16;
    char* wsb0 = (char*)Ws + (size_t)(0 * 256 + wave * 64) * 16;
    char* wsb1 = (char*)Ws + (size_t)(1 * 256 + wave * 64) * 16;

    floatx4 acc[4][4];
#pragma unroll
    for (int i = 0; i < 4; i++)
#pragma unroll
        for (int j = 0; j < 4; j++) acc[i][j] = (floatx4)(0.f);

#pragma unroll 2
    for (int k0 = 0; k0 < K; k0 += 32) {
        int ks = k0 + lkc * 8;
        g2lds16(A + (size_t)ar0 * K + ks, asb0);
        g2lds16(A + (size_t)ar1 * K + ks, asb1);
        g2lds16(W + (size_t)wr0 * K + ks, wsb0);
        g2lds16(W + (size_t)wr1 * K + ks, wsb1);
        __syncthreads();

        short8 af[4], wf[4];
#pragma unroll
        for (int mt = 0; mt < 4; mt++) af[mt] = As[(wm * 4 + mt) * 64 + rslot];
#pragma unroll
        for (int nt = 0; nt < 4; nt++) wf[nt] = Ws[(wn * 4 + nt) * 64 + rslot];
#pragma unroll
        for (int mt = 0; mt < 4; mt++)
#pragma unroll
            for (int nt = 0; nt < 4; nt++)
                acc[mt][nt] = __builtin_amdgcn_mfma_f32_16x16x32_bf16(
                    af[mt], wf[nt], acc[mt][nt], 0, 0, 0);
        __syncthreads();
    }

    // C/D layout: col=lane&15, row=(lane>>4)*4+reg
    int ccol = lr;
    int r0 = lkc * 4;
#pragma unroll
    for (int mt = 0; mt < 4; mt++) {
#pragma unroll
        for (int reg = 0; reg < 4; reg++) {
            int row = rowbase + (wm * 4 + mt) * 16 + r0 + reg;
            if (row >= M) continue;
#pragma unroll
            for (int nt = 0; nt < 4; nt++) {
                int col = colbase + (wn * 4 + nt) * 16 + ccol;
                float v = acc[mt][nt][reg] + bias[col];
                Cbf[(size_t)row * 256 + col] = f2bf(fmaxf(v, 0.f));
            }
        }
    }
}

// ------- fused mean-pool + MLP head: one block (256 thr) per graph ---------
__global__ __launch_bounds__(256) void pool_head(
    const unsigned short* __restrict__ h, const int* __restrict__ batch,
    const float* __restrict__ Wf1, const float* __restrict__ bf1,
    const float* __restrict__ Wf2, const float* __restrict__ bf2,
    float* __restrict__ out) {
    __shared__ float hg[256];
    __shared__ float hid[128];
    int g = blockIdx.x;
    int t = threadIdx.x;
    int lo = 0, hi = N_NODES;
    while (lo < hi) { int m = (lo + hi) >> 1; if (batch[m] < g) lo = m + 1; else hi = m; }
    int start = lo;
    lo = 0; hi = N_NODES;
    while (lo < hi) { int m = (lo + hi) >> 1; if (batch[m] < g + 1) lo = m + 1; else hi = m; }
    int end = lo;
    float acc = 0.f;
    for (int r = start; r < end; ++r) acc += bf2f(h[(size_t)r * 256 + t]);
    hg[t] = acc / fmaxf((float)(end - start), 1.0f);
    __syncthreads();
    if (t < 128) {
        float a1 = bf1[t];
        for (int c = 0; c < 256; c++) a1 += hg[c] * Wf1[t * 256 + c];
        hid[t] = fmaxf(a1, 0.f);
    }
    __syncthreads();
    if (t < 10) {
        float a = bf2[t];
        for (int j = 0; j < 128; j++) a += hid[j] * Wf2[t * 128 + j];
        out[g * 10 + t] = a;
    }
}

extern "C" void kernel_launch(void* const* d_in, const int* in_sizes, int n_in,
                              void* d_out, int out_size, void* d_ws, size_t ws_size,
                              hipStream_t stream) {
    const float* x   = (const float*)d_in[0];
    const int*  edge = (const int*)d_in[1];
    const int*  batch= (const int*)d_in[2];
    const float* W1  = (const float*)d_in[3];
    const float* b1  = (const float*)d_in[4];
    const float* W2  = (const float*)d_in[5];
    const float* b2  = (const float*)d_in[6];
    const float* W3  = (const float*)d_in[7];
    const float* b3  = (const float*)d_in[8];
    const float* Wf1 = (const float*)d_in[9];
    const float* bf1 = (const float*)d_in[10];
    const float* Wf2 = (const float*)d_in[11];
    const float* bf2 = (const float*)d_in[12];
    const int* src = edge;
    const int* dst = edge + N_EDGES;

    char* wsb = (char*)d_ws;
    size_t off = 0;
    auto alloc = [&](size_t bytes) { void* p = wsb + off; off += (bytes + 255) & ~(size_t)255; return p; };
    unsigned short* x_bf  = (unsigned short*)alloc((size_t)N_NODES * 128 * 2);
    unsigned short* agg_bf= (unsigned short*)alloc((size_t)N_NODES * 256 * 2);
    unsigned short* hA_bf = (unsigned short*)alloc((size_t)N_NODES * 256 * 2);
    unsigned short* hB_bf = (unsigned short*)alloc((size_t)N_NODES * 256 * 2);
    unsigned short* W1bf  = (unsigned short*)alloc(256 * 128 * 2);
    unsigned short* W2bf  = (unsigned short*)alloc(256 * 256 * 2);
    unsigned short* W3bf  = (unsigned short*)alloc(256 * 256 * 2);
    int* rowptr   = (int*)alloc((N_NODES + 4) * 4);
    int* cursor   = (int*)alloc(N_NODES * 4);
    int* deg      = (int*)alloc(N_NODES * 4);
    int* csr      = (int*)alloc(N_EDGES * 4);
    int* blocksum = (int*)alloc(64 * 4);

    const int NB_SCAN = (N_NODES + 1023) / 1024;  // 49

    // ---- CSR build (by dst) ----
    hipMemsetAsync(deg, 0, N_NODES * sizeof(int), stream);
    deg_hist<<<(N_EDGES + 255) / 256, 256, 0, stream>>>(dst, deg);
    scan1<<<NB_SCAN, 1024, 0, stream>>>(deg, rowptr, blocksum);
    scan2<<<1, 64, 0, stream>>>(blocksum, NB_SCAN);
    scan3<<<NB_SCAN, 1024, 0, stream>>>(rowptr, blocksum, cursor);
    scatter_csr<<<(N_EDGES + 255) / 256, 256, 0, stream>>>(src, dst, cursor, csr);

    // ---- converts (x + all weights, one launch) ----
    convert_all<<<(1640960 + 255) / 256, 256, 0, stream>>>(x, W1, W2, W3, x_bf, W1bf, W2bf, W3bf);

    dim3 ggrid((N_NODES + 127) / 128, 2);  // 391 x 2

    // ---- layer 1 (K=128) ----
    gather_bf<128><<<(N_NODES + 15) / 16, 256, 0, stream>>>(x_bf, rowptr, csr, agg_bf);
    gemm_mfma<128><<<ggrid, 256, 0, stream>>>(agg_bf, W1bf, b1, hA_bf, N_NODES);

    // ---- layer 2 (K=256) ----
    gather_bf<256><<<(N_NODES + 7) / 8, 256, 0, stream>>>(hA_bf, rowptr, csr, agg_bf);
    gemm_mfma<256><<<ggrid, 256, 0, stream>>>(agg_bf, W2bf, b2, hB_bf, N_NODES);

    // ---- layer 3 (K=256) ----
    gather_bf<256><<<(N_NODES + 7) / 8, 256, 0, stream>>>(hB_bf, rowptr, csr, agg_bf);
    gemm_mfma<256><<<ggrid, 256, 0, stream>>>(agg_bf, W3bf, b3, hA_bf, N_NODES);

    // ---- fused mean pool + head ----
    pool_head<<<N_GRAPHS, 256, 0, stream>>>(hA_bf, batch, Wf1, bf1, Wf2, bf2, (float*)d_out);
}